// Round 6
// baseline (486.906 us; speedup 1.0000x reference)
//
#include <hip/hip_runtime.h>
#include <stdint.h>

typedef __attribute__((ext_vector_type(8))) short short8;
typedef __attribute__((ext_vector_type(4))) float floatx4;

__device__ inline unsigned short f2bf(float f){
  union { float fv; unsigned int u; } v; v.fv = f;
  unsigned int u = v.u;
  unsigned int r = ((u >> 16) & 1u) + 0x7FFFu;
  return (unsigned short)((u + r) >> 16);
}

// async global->LDS, 16B per lane, dest = wave-uniform base + lane*16
__device__ __forceinline__ void async16(const void* g, void* l){
  __builtin_amdgcn_global_load_lds(
      (const __attribute__((address_space(1))) unsigned int*)g,
      (__attribute__((address_space(3))) unsigned int*)l, 16, 0, 0);
}

#define PBAR(N) do {                                              \
    asm volatile("s_waitcnt vmcnt(" #N ")" ::: "memory");          \
    __builtin_amdgcn_s_barrier();                                  \
    asm volatile("" ::: "memory");                                 \
  } while (0)

// ---------------- weight prep ----------------
__global__ void prep_w1(const float* __restrict__ w, unsigned short* __restrict__ w1p){
  int i = blockIdx.x*256 + threadIdx.x;
  if (i >= 192*192) return;
  int k = i % 192, o = i / 192;
  int cc = k >> 3, kx = k & 7;
  unsigned short v = 0;
  if (cc < 21 && kx < 7){
    int c = cc / 7, ky = cc % 7;
    v = f2bf(w[(o*3 + c)*49 + ky*7 + kx]);
  }
  w1p[i] = v;
}
__global__ void prep_w2(const float* __restrict__ w, unsigned short* __restrict__ w2p){
  int i = blockIdx.x*256 + threadIdx.x;
  if (i >= 192*9408) return;
  int k = i % 9408, o = i / 9408;
  int g = k / 192, c = k % 192;
  int ky = g / 7, kx = g % 7;
  w2p[i] = f2bf(w[((o*192 + c)*7 + ky)*7 + kx]);
}
__global__ void prep_w3(const float* __restrict__ w, unsigned short* __restrict__ w3p){
  int i = blockIdx.x*256 + threadIdx.x;
  if (i >= 768*8640) return;
  int k = i % 8640, o = i / 8640;
  int g = k / 960, c = k % 960;
  int ky = g / 3, kx = g % 3;
  w3p[i] = f2bf(w[((o*960 + c)*3 + ky)*3 + kx]);
}
__global__ void prep_zp(unsigned int* __restrict__ zp){
  zp[threadIdx.x] = 0u;  // 256 B zero page
}
__global__ void zero_f32(float* __restrict__ p, int n){
  int i = blockIdx.x*256 + threadIdx.x;
  if (i < n) p[i] = 0.f;
}

// ---------------- pad+im2col-kx: x -> xh2[b][c][iy(230)][ox(56)][kx(8)] bf16 ----------------
__global__ void pad_x2(const float* __restrict__ x, unsigned short* __restrict__ xh2){
  int idx = blockIdx.x*256 + threadIdx.x;
  if (idx >= 64*3*230*56*8) return;
  int kx = idx & 7; int t = idx >> 3;
  int ox = t % 56;  t /= 56;
  int iy = t % 230; t /= 230;      // t = b*3 + c
  int row = iy - 3;
  int col = 4*ox - 3 + kx;
  unsigned short v = 0;
  if (row >= 0 && row < 224 && col >= 0 && col < 224)
    v = f2bf(x[((size_t)t*224 + row)*224 + col]);
  xh2[idx] = v;
}

// ---------------- wavelet: per 16x16 block 2D WHT / 16 ----------------
__global__ void wavelet_kernel(const float* __restrict__ x, unsigned short* __restrict__ feat){
  int blk = blockIdx.x;
  int j = blk % 14; blk /= 14;
  int i = blk % 14; blk /= 14;
  int c = blk % 3;  int b = blk / 3;
  int t = threadIdx.x;
  int u = t >> 4, v = t & 15;
  float val = x[((size_t)(b*3 + c)*224 + (i*16 + u))*224 + (j*16 + v)];
  #pragma unroll
  for (int bit = 1; bit < 64; bit <<= 1){
    float p = __shfl_xor(val, bit);
    val = (t & bit) ? (p - val) : (val + p);
  }
  __shared__ float s[256];
  #pragma unroll
  for (int bit = 64; bit < 256; bit <<= 1){
    s[t] = val; __syncthreads();
    float p = s[t ^ bit]; __syncthreads();
    val = (t & bit) ? (p - val) : (val + p);
  }
  s[t] = val; __syncthreads();
  int k = t;
  int d1 = (k>>6)&3, d2 = (k>>4)&3, d3 = (k>>2)&3, d4 = k&3;
  int mr = (d1>>1) | ((d2>>1)<<1) | ((d3>>1)<<2) | ((d4>>1)<<3);
  int mc = (d1&1)  | ((d2&1)<<1)  | ((d3&1)<<2)  | ((d4&1)<<3);
  float outv = s[mr*16 + mc] * 0.0625f;
  feat[((size_t)((b*14 + i)*14 + j))*960 + (k*3 + c)] = f2bf(outv);
}

// ---------------- conv1: dbuf glds MFMA GEMM, BM=128 BN=64 K=192 (3 iters) ----------------
__global__ __launch_bounds__(256) void conv1_gemm(const unsigned short* __restrict__ xh2,
                                                  const unsigned short* __restrict__ w1p,
                                                  const float* __restrict__ b1,
                                                  unsigned short* __restrict__ sp1){
  __shared__ unsigned short As[2][128*64], Bs[2][64*64];
  int m0 = blockIdx.x*128, n0 = blockIdx.y*64;
  int tid = threadIdx.x, wave = tid >> 6, lane = tid & 63;
  int l16 = lane & 15, quad = lane >> 4;
  int wy = wave >> 1, wx = wave & 1;
  int r8 = lane >> 3, kb = (lane & 7) ^ r8;

  int Abase[4];
  #pragma unroll
  for (int j = 0; j < 4; j++){
    int row = wave*32 + j*8 + r8;
    int m = m0 + row;
    int ox = m % 56; int t = m / 56; int oy = t % 56; int b = t / 56;
    Abase[j] = (b*690 + 4*oy)*448 + ox*8;
  }
  const unsigned short* pB0 = w1p + (n0 + wave*16 + r8)*192 + kb*8;
  const unsigned short* pB1 = pB0 + 8*192;

  int sw = l16 & 7;
  int xo0 = ((quad    ) ^ sw)*8;
  int xo1 = ((quad + 4) ^ sw)*8;
  int aoff[4];
  #pragma unroll
  for (int mt = 0; mt < 4; mt++) aoff[mt] = (wy*64 + mt*16 + l16)*64;
  int boff0 = (wx*32 + l16)*64, boff1 = boff0 + 16*64;

  floatx4 acc[4][2];
  #pragma unroll
  for (int mt = 0; mt < 4; mt++)
    #pragma unroll
    for (int nt = 0; nt < 2; nt++) acc[mt][nt] = (floatx4){0.f,0.f,0.f,0.f};

  auto stage = [&](int i, int buf){
    int cc = i*8 + kb;
    int c = (cc*147) >> 10;
    int ky = cc - 7*c;
    int koff = (c*230 + ky)*448;
    #pragma unroll
    for (int j = 0; j < 4; j++)
      async16(xh2 + Abase[j] + koff, (void*)&As[buf][(wave*32 + j*8)*64]);
    async16(pB0 + i*64, (void*)&Bs[buf][(wave*16    )*64]);
    async16(pB1 + i*64, (void*)&Bs[buf][(wave*16 + 8)*64]);
  };

  stage(0, 0);
  __syncthreads();
  #pragma unroll
  for (int i = 0; i < 3; i++){
    int buf = i & 1;
    if (i < 2) stage(i+1, buf ^ 1);
    #pragma unroll
    for (int ks = 0; ks < 2; ks++){
      int xo = ks ? xo1 : xo0;
      short8 b0 = *(const short8*)&Bs[buf][boff0 + xo];
      short8 b1 = *(const short8*)&Bs[buf][boff1 + xo];
      #pragma unroll
      for (int mt = 0; mt < 4; mt++){
        short8 a = *(const short8*)&As[buf][aoff[mt] + xo];
        acc[mt][0] = __builtin_amdgcn_mfma_f32_16x16x32_bf16(a, b0, acc[mt][0], 0, 0, 0);
        acc[mt][1] = __builtin_amdgcn_mfma_f32_16x16x32_bf16(a, b1, acc[mt][1], 0, 0, 0);
      }
    }
    __syncthreads();
  }

  #pragma unroll
  for (int mt = 0; mt < 4; mt++){
    #pragma unroll
    for (int rg = 0; rg < 4; rg++){
      int row = wy*64 + mt*16 + quad*4 + rg;
      size_t ob = (size_t)(m0 + row)*192;
      #pragma unroll
      for (int nt = 0; nt < 2; nt++){
        int nn = n0 + wx*32 + nt*16 + l16;
        sp1[ob + nn] = f2bf(acc[mt][nt][rg] + b1[nn]);
      }
    }
  }
}

// ---------------- conv2/conv3: BM=128 BN=96 BK=64, K-split x3 across blocks ----------------
// m97-verified pipeline shape: stage(i+1) -> compute(i) -> [vmcnt(0)+barrier].
// 2 buffers (56 KB LDS -> 2 blocks/CU). 4 waves in a 2x2 grid, each owning a
// 64x48 quadrant: acc[4][3], 24 MFMA/wave/body. Staging/swizzle algebra is the
// round-0-verified pattern (A: conv1's exact 4-glds/wave strips; B: 3 glds).
// bytes/FLOP = (128+96)/(128*96) vs (64+64)/(64*64): -42% global feed per FLOP.
// Each block covers K3=K/3 (integer bodies for both convs); f32 atomicAdd into
// a pre-zeroed partial buffer; combine kernel applies bias(/pos) + cast.
template<int MODE>
__global__ __launch_bounds__(256) void conv_split(const unsigned short* __restrict__ Ain,
                                                  const unsigned short* __restrict__ Bt,
                                                  const unsigned short* __restrict__ zp,
                                                  float* __restrict__ pout){
  constexpr int OH  = (MODE==2) ? 14 : 7;
  constexpr int OW  = OH;
  constexpr int IH  = (MODE==2) ? 56 : 14;
  constexpr int IW  = IH;
  constexpr int Cin = (MODE==2) ? 192 : 960;
  constexpr int KW  = (MODE==2) ? 7 : 3;
  constexpr int S   = (MODE==2) ? 4 : 2;
  constexpr int P   = (MODE==2) ? 3 : 1;
  constexpr int K   = (MODE==2) ? 9408 : 8640;
  constexpr int K3  = K/3;               // 3136 / 2880
  constexpr int NB  = K3/64;             // 49 / 45 (exact)
  constexpr int MTI = (MODE==2) ? 98 : 25;
  constexpr int NTI = (MODE==2) ? 2 : 8;
  constexpr int M   = (MODE==2) ? 12544 : 3136;
  constexpr int NF  = (MODE==2) ? 192 : 768;

  int id = blockIdx.x;
  int mtile = id % MTI;
  int kn = id / MTI;
  int kseg = kn / NTI, ntile = kn % NTI;
  int m0 = mtile*128, n0 = ntile*96;

  __shared__ unsigned short As[2][128*64], Bs[2][96*64];   // 32 KB + 24 KB
  int tid = threadIdx.x, wv = tid >> 6, lane = tid & 63;
  int l16 = lane & 15, quad = lane >> 4;
  int wy = wv >> 1, wx = wv & 1;
  int r8 = lane >> 3, kb = (lane & 7) ^ r8;
  int sw = l16 & 7;

  // A staging: wave wv stages rows [wv*32, wv*32+32) in 4 glds (conv1 pattern)
  int abase[4], iyb[4], ixb[4];
  #pragma unroll
  for (int j = 0; j < 4; j++){
    int r = wv*32 + j*8 + r8;
    int m = m0 + r; if (m > M-1) m = M-1;           // conv3 tail clamp (reads only)
    int ox = m % OW; int t = m / OW; int oy = t % OH; int bb = t / OH;
    iyb[j] = S*oy - P; ixb[j] = S*ox - P;
    abase[j] = ((bb*IH + iyb[j])*IW + ixb[j])*Cin + kb*8;
  }
  // B staging: wave wv stages rows [wv*24, wv*24+24) in 3 glds
  const unsigned short* pB[3];
  #pragma unroll
  for (int j = 0; j < 3; j++)
    pB[j] = Bt + (size_t)(n0 + wv*24 + j*8 + r8)*K + kseg*K3 + kb*8;

  // k-state for this K-segment (BK=64 divides Cin for both convs)
  int k0 = kseg*K3;
  int c0 = k0 % Cin;
  int gk = k0 / Cin;
  int kx = gk % KW, ky = gk / KW;
  int k0n = 0;

  floatx4 acc[4][3];
  #pragma unroll
  for (int mt = 0; mt < 4; mt++)
    #pragma unroll
    for (int nt = 0; nt < 3; nt++) acc[mt][nt] = (floatx4){0.f,0.f,0.f,0.f};

  auto stage = [&](int buf){
    int koff = (ky*IW + kx)*Cin + c0;
    #pragma unroll
    for (int j = 0; j < 4; j++){
      int iy = iyb[j] + ky, ix = ixb[j] + kx;
      const unsigned short* pa = ((unsigned)iy < (unsigned)IH && (unsigned)ix < (unsigned)IW)
                                 ? (Ain + abase[j] + koff) : zp;
      async16(pa, (void*)&As[buf][(wv*32 + j*8)*64]);
    }
    #pragma unroll
    for (int j = 0; j < 3; j++)
      async16(pB[j] + k0n, (void*)&Bs[buf][(wv*24 + j*8)*64]);
    k0n += 64;
    c0 += 64;
    if (c0 == Cin){ c0 = 0; kx++; if (kx == KW){ kx = 0; ky++; } }
  };

  auto compute = [&](int buf){
    #pragma unroll
    for (int ks = 0; ks < 2; ks++){
      int xo = ((ks*4 + quad) ^ sw)*8;
      short8 b0 = *(const short8*)&Bs[buf][(wx*48      + l16)*64 + xo];
      short8 b1 = *(const short8*)&Bs[buf][(wx*48 + 16 + l16)*64 + xo];
      short8 b2 = *(const short8*)&Bs[buf][(wx*48 + 32 + l16)*64 + xo];
      #pragma unroll
      for (int mt = 0; mt < 4; mt++){
        short8 a = *(const short8*)&As[buf][(wy*64 + mt*16 + l16)*64 + xo];
        acc[mt][0] = __builtin_amdgcn_mfma_f32_16x16x32_bf16(a, b0, acc[mt][0], 0, 0, 0);
        acc[mt][1] = __builtin_amdgcn_mfma_f32_16x16x32_bf16(a, b1, acc[mt][1], 0, 0, 0);
        acc[mt][2] = __builtin_amdgcn_mfma_f32_16x16x32_bf16(a, b2, acc[mt][2], 0, 0, 0);
      }
    }
  };

  // m97 schedule: prologue stage+drain; per body: stage(next) || compute(cur),
  // then drain+barrier (drain overlaps the 24-MFMA compute just issued above it).
  stage(0);
  PBAR(0);
  for (int i = 0; i < NB; i++){
    if (i + 1 < NB) stage((i+1) & 1);
    compute(i & 1);
    PBAR(0);
  }

  // epilogue: f32 atomic accumulate into pre-zeroed partials
  #pragma unroll
  for (int mt = 0; mt < 4; mt++){
    #pragma unroll
    for (int rg = 0; rg < 4; rg++){
      int row = wy*64 + mt*16 + quad*4 + rg;
      int mm = m0 + row;
      #pragma unroll
      for (int nt = 0; nt < 3; nt++){
        int nn = n0 + wx*48 + nt*16 + l16;
        atomicAdd(&pout[(size_t)mm*NF + nn], acc[mt][nt][rg]);
      }
    }
  }
}

// ---------------- combine kernels ----------------
__global__ void comb2(const float* __restrict__ pc, const float* __restrict__ bias,
                      unsigned short* __restrict__ feat){
  int i = blockIdx.x*256 + threadIdx.x;           // 12544*192 = 2408448 exact
  int n = i % 192, m = i / 192;
  feat[(size_t)m*960 + 768 + n] = f2bf(pc[i] + bias[n]);
}
__global__ void comb3(const float* __restrict__ pc, const float* __restrict__ bias,
                      const float* __restrict__ pos, float* __restrict__ out){
  int i = blockIdx.x*256 + threadIdx.x;           // 3136*768 = 2408448 exact
  int n = i % 768, m = i / 768;
  int b2 = m / 49, tt = m - b2*49;
  float v = pc[(size_t)m*768 + n] + bias[n] + pos[(size_t)(1 + tt)*768 + n];
  out[((size_t)(m + b2 + 1))*768 + n] = v;
}

// ---------------- cls row ----------------
__global__ void cls_kernel(const float* __restrict__ cls, const float* __restrict__ pos,
                           float* __restrict__ out){
  int i = blockIdx.x*256 + threadIdx.x;
  if (i >= 64*768) return;
  int e = i % 768, b = i / 768;
  out[(size_t)(b*50)*768 + e] = cls[e] + pos[e];
}

extern "C" void kernel_launch(void* const* d_in, const int* in_sizes, int n_in,
                              void* d_out, int out_size, void* d_ws, size_t ws_size,
                              hipStream_t stream){
  (void)in_sizes; (void)n_in; (void)out_size;
  const float* x    = (const float*)d_in[0];
  const float* w_s1 = (const float*)d_in[1];
  const float* b_s1 = (const float*)d_in[2];
  const float* w_s2 = (const float*)d_in[3];
  const float* b_s2 = (const float*)d_in[4];
  const float* w_p  = (const float*)d_in[5];
  const float* b_p  = (const float*)d_in[6];
  const float* cls  = (const float*)d_in[7];
  const float* pos  = (const float*)d_in[8];
  float* out = (float*)d_out;

  char* ws = (char*)d_ws;
  if (ws_size < 118235136u) return;
  unsigned short* w1p  = (unsigned short*)(ws + 0);
  unsigned short* sp1  = (unsigned short*)(ws + 131072);      // 77.07 MB, dead after conv2
  unsigned short* zp   = (unsigned short*)(ws + 77201408u);
  unsigned short* w2p  = (unsigned short*)(ws + 77266944u);   // 3.6 MB
  unsigned short* w3p  = (unsigned short*)(ws + 80879616u);   // 13.3 MB, written AFTER comb2
  unsigned short* feat = (unsigned short*)(ws + 94150656u);   // 24.1 MB
  unsigned short* xh2  = (unsigned short*)(ws + 77266944u);   // aliases w2p+ (dead by then)
  float* pc2 = (float*)(ws + 80879616u);   // 9.63 MB in w3p's slot (w3p written later)
  float* pc3 = (float*)(ws + 131072);      // 9.83 MB in sp1's region (sp1 dead after conv2)

  prep_w1<<<(192*192 + 255)/256, 256, 0, stream>>>(w_s1, w1p);
  pad_x2<<<(64*3*230*56*8)/256, 256, 0, stream>>>(x, xh2);
  conv1_gemm<<<dim3(1568, 3), 256, 0, stream>>>(xh2, w1p, b_s1, sp1);
  prep_w2<<<(192*9408 + 255)/256, 256, 0, stream>>>(w_s2, w2p);
  prep_zp<<<1, 64, 0, stream>>>((unsigned int*)zp);
  wavelet_kernel<<<64*3*14*14, 256, 0, stream>>>(x, feat);

  zero_f32<<<9408, 256, 0, stream>>>(pc2, 12544*192);
  conv_split<2><<<588, 256, 0, stream>>>(sp1, w2p, zp, pc2);
  comb2<<<9408, 256, 0, stream>>>(pc2, b_s2, feat);

  prep_w3<<<(768*8640 + 255)/256, 256, 0, stream>>>(w_p, w3p);   // overwrites pc2 (dead)
  zero_f32<<<9600, 256, 0, stream>>>(pc3, 3200*768);
  conv_split<3><<<600, 256, 0, stream>>>(feat, w3p, zp, pc3);
  comb3<<<9408, 256, 0, stream>>>(pc3, b_p, pos, out);
  cls_kernel<<<(64*768 + 255)/256, 256, 0, stream>>>(cls, pos, out);
}

// Round 7
// 457.255 us; speedup vs baseline: 1.0648x; 1.0648x over previous
//
#include <hip/hip_runtime.h>
#include <stdint.h>

typedef __attribute__((ext_vector_type(8))) short short8;
typedef __attribute__((ext_vector_type(4))) float floatx4;

__device__ inline unsigned short f2bf(float f){
  union { float fv; unsigned int u; } v; v.fv = f;
  unsigned int u = v.u;
  unsigned int r = ((u >> 16) & 1u) + 0x7FFFu;
  return (unsigned short)((u + r) >> 16);
}

// async global->LDS, 16B per lane, dest = wave-uniform base + lane*16
__device__ __forceinline__ void async16(const void* g, void* l){
  __builtin_amdgcn_global_load_lds(
      (const __attribute__((address_space(1))) unsigned int*)g,
      (__attribute__((address_space(3))) unsigned int*)l, 16, 0, 0);
}

// counted-vmcnt barrier: keep N VMEM ops in flight across the barrier.
#define PBAR(N) do {                                              \
    asm volatile("s_waitcnt vmcnt(" #N ")" ::: "memory");          \
    __builtin_amdgcn_s_barrier();                                  \
    asm volatile("" ::: "memory");                                 \
  } while (0)

// ---------------- weight prep ----------------
__global__ void prep_w1(const float* __restrict__ w, unsigned short* __restrict__ w1p){
  int i = blockIdx.x*256 + threadIdx.x;
  if (i >= 192*192) return;
  int k = i % 192, o = i / 192;
  int cc = k >> 3, kx = k & 7;
  unsigned short v = 0;
  if (cc < 21 && kx < 7){
    int c = cc / 7, ky = cc % 7;
    v = f2bf(w[(o*3 + c)*49 + ky*7 + kx]);
  }
  w1p[i] = v;
}
__global__ void prep_w2(const float* __restrict__ w, unsigned short* __restrict__ w2p){
  int i = blockIdx.x*256 + threadIdx.x;
  if (i >= 192*9408) return;
  int k = i % 9408, o = i / 9408;
  int g = k / 192, c = k % 192;
  int ky = g / 7, kx = g % 7;
  w2p[i] = f2bf(w[((o*192 + c)*7 + ky)*7 + kx]);
}
__global__ void prep_w3(const float* __restrict__ w, unsigned short* __restrict__ w3p){
  int i = blockIdx.x*256 + threadIdx.x;
  if (i >= 768*8640) return;
  int k = i % 8640, o = i / 8640;
  int g = k / 960, c = k % 960;
  int ky = g / 3, kx = g % 3;
  w3p[i] = f2bf(w[((o*960 + c)*3 + ky)*3 + kx]);
}
__global__ void prep_zp(unsigned int* __restrict__ zp){
  zp[threadIdx.x] = 0u;  // 256 B zero page
}
__global__ void zero_f32(float* __restrict__ p, int n){
  int i = blockIdx.x*256 + threadIdx.x;
  if (i < n) p[i] = 0.f;
}

// ---------------- pad+im2col-kx: x -> xh2[b][c][iy(230)][ox(56)][kx(8)] bf16 ----------------
__global__ void pad_x2(const float* __restrict__ x, unsigned short* __restrict__ xh2){
  int idx = blockIdx.x*256 + threadIdx.x;
  if (idx >= 64*3*230*56*8) return;
  int kx = idx & 7; int t = idx >> 3;
  int ox = t % 56;  t /= 56;
  int iy = t % 230; t /= 230;      // t = b*3 + c
  int row = iy - 3;
  int col = 4*ox - 3 + kx;
  unsigned short v = 0;
  if (row >= 0 && row < 224 && col >= 0 && col < 224)
    v = f2bf(x[((size_t)t*224 + row)*224 + col]);
  xh2[idx] = v;
}

// ---------------- wavelet: per 16x16 block 2D WHT / 16 ----------------
__global__ void wavelet_kernel(const float* __restrict__ x, unsigned short* __restrict__ feat){
  int blk = blockIdx.x;
  int j = blk % 14; blk /= 14;
  int i = blk % 14; blk /= 14;
  int c = blk % 3;  int b = blk / 3;
  int t = threadIdx.x;
  int u = t >> 4, v = t & 15;
  float val = x[((size_t)(b*3 + c)*224 + (i*16 + u))*224 + (j*16 + v)];
  #pragma unroll
  for (int bit = 1; bit < 64; bit <<= 1){
    float p = __shfl_xor(val, bit);
    val = (t & bit) ? (p - val) : (val + p);
  }
  __shared__ float s[256];
  #pragma unroll
  for (int bit = 64; bit < 256; bit <<= 1){
    s[t] = val; __syncthreads();
    float p = s[t ^ bit]; __syncthreads();
    val = (t & bit) ? (p - val) : (val + p);
  }
  s[t] = val; __syncthreads();
  int k = t;
  int d1 = (k>>6)&3, d2 = (k>>4)&3, d3 = (k>>2)&3, d4 = k&3;
  int mr = (d1>>1) | ((d2>>1)<<1) | ((d3>>1)<<2) | ((d4>>1)<<3);
  int mc = (d1&1)  | ((d2&1)<<1)  | ((d3&1)<<2)  | ((d4&1)<<3);
  float outv = s[mr*16 + mc] * 0.0625f;
  feat[((size_t)((b*14 + i)*14 + j))*960 + (k*3 + c)] = f2bf(outv);
}

// ---------------- conv1: dbuf glds MFMA GEMM, BM=128 BN=64 K=192 (3 iters) ----------------
__global__ __launch_bounds__(256) void conv1_gemm(const unsigned short* __restrict__ xh2,
                                                  const unsigned short* __restrict__ w1p,
                                                  const float* __restrict__ b1,
                                                  unsigned short* __restrict__ sp1){
  __shared__ unsigned short As[2][128*64], Bs[2][64*64];
  int m0 = blockIdx.x*128, n0 = blockIdx.y*64;
  int tid = threadIdx.x, wave = tid >> 6, lane = tid & 63;
  int l16 = lane & 15, quad = lane >> 4;
  int wy = wave >> 1, wx = wave & 1;
  int r8 = lane >> 3, kb = (lane & 7) ^ r8;

  int Abase[4];
  #pragma unroll
  for (int j = 0; j < 4; j++){
    int row = wave*32 + j*8 + r8;
    int m = m0 + row;
    int ox = m % 56; int t = m / 56; int oy = t % 56; int b = t / 56;
    Abase[j] = (b*690 + 4*oy)*448 + ox*8;
  }
  const unsigned short* pB0 = w1p + (n0 + wave*16 + r8)*192 + kb*8;
  const unsigned short* pB1 = pB0 + 8*192;

  int sw = l16 & 7;
  int xo0 = ((quad    ) ^ sw)*8;
  int xo1 = ((quad + 4) ^ sw)*8;
  int aoff[4];
  #pragma unroll
  for (int mt = 0; mt < 4; mt++) aoff[mt] = (wy*64 + mt*16 + l16)*64;
  int boff0 = (wx*32 + l16)*64, boff1 = boff0 + 16*64;

  floatx4 acc[4][2];
  #pragma unroll
  for (int mt = 0; mt < 4; mt++)
    #pragma unroll
    for (int nt = 0; nt < 2; nt++) acc[mt][nt] = (floatx4){0.f,0.f,0.f,0.f};

  auto stage = [&](int i, int buf){
    int cc = i*8 + kb;
    int c = (cc*147) >> 10;
    int ky = cc - 7*c;
    int koff = (c*230 + ky)*448;
    #pragma unroll
    for (int j = 0; j < 4; j++)
      async16(xh2 + Abase[j] + koff, (void*)&As[buf][(wave*32 + j*8)*64]);
    async16(pB0 + i*64, (void*)&Bs[buf][(wave*16    )*64]);
    async16(pB1 + i*64, (void*)&Bs[buf][(wave*16 + 8)*64]);
  };

  stage(0, 0);
  __syncthreads();
  #pragma unroll
  for (int i = 0; i < 3; i++){
    int buf = i & 1;
    if (i < 2) stage(i+1, buf ^ 1);
    #pragma unroll
    for (int ks = 0; ks < 2; ks++){
      int xo = ks ? xo1 : xo0;
      short8 b0 = *(const short8*)&Bs[buf][boff0 + xo];
      short8 b1 = *(const short8*)&Bs[buf][boff1 + xo];
      #pragma unroll
      for (int mt = 0; mt < 4; mt++){
        short8 a = *(const short8*)&As[buf][aoff[mt] + xo];
        acc[mt][0] = __builtin_amdgcn_mfma_f32_16x16x32_bf16(a, b0, acc[mt][0], 0, 0, 0);
        acc[mt][1] = __builtin_amdgcn_mfma_f32_16x16x32_bf16(a, b1, acc[mt][1], 0, 0, 0);
      }
    }
    __syncthreads();
  }

  #pragma unroll
  for (int mt = 0; mt < 4; mt++){
    #pragma unroll
    for (int rg = 0; rg < 4; rg++){
      int row = wy*64 + mt*16 + quad*4 + rg;
      size_t ob = (size_t)(m0 + row)*192;
      #pragma unroll
      for (int nt = 0; nt < 2; nt++){
        int nn = n0 + wx*32 + nt*16 + l16;
        sp1[ob + nn] = f2bf(acc[mt][nt][rg] + b1[nn]);
      }
    }
  }
}

// ---------------- conv2/conv3: BM=128 BN=64 BK=32, 3-buf depth-2 PBAR(3), K-split x2 ----------------
// Depth-2 counted pipeline (round-0-proven invariant): 3 glds/wave/body, 6 in
// flight at each barrier, PBAR(3) => tile i landed, tile i+1 in flight. LDS
// 3 x (8K A + 4K B) = 36 KB -> 4 blocks/CU (2x round-0 occupancy). Per wave:
// 64x32 quadrant, 8 MFMA + 6 ds_read_b128 + 3 glds per body (round-0 mix) at
// 23.4 B/kFLOP staged (round 0: 31.3). BK=32 rows are 64 B = 4 granules;
// store position p holds source granule p ^ ((row>>1)&3); read granule q at
// position q ^ ((row>>1)&3) => exactly 2 lanes per 16B slot per read (free).
// K-split x2 across blocks, f32 atomicAdd into pre-zeroed partials + comb
// (machinery proven in round 6). Round-0 grid grouping (8 mtiles x NTI).
template<int MODE>
__global__ __launch_bounds__(256, 4) void conv_ks(const unsigned short* __restrict__ Ain,
                                                  const unsigned short* __restrict__ Bt,
                                                  const unsigned short* __restrict__ zp,
                                                  float* __restrict__ pout){
  constexpr int OH  = (MODE==2) ? 14 : 7;
  constexpr int OW  = OH;
  constexpr int IH  = (MODE==2) ? 56 : 14;
  constexpr int IW  = IH;
  constexpr int Cin = (MODE==2) ? 192 : 960;
  constexpr int KW  = (MODE==2) ? 7 : 3;
  constexpr int S   = (MODE==2) ? 4 : 2;
  constexpr int P   = (MODE==2) ? 3 : 1;
  constexpr int K   = (MODE==2) ? 9408 : 8640;
  constexpr int K2  = K/2;                 // 4704 / 4320
  constexpr int NB  = K2/32;               // 147 / 135 (exact)
  constexpr int MTI = (MODE==2) ? 98 : 25;
  constexpr int NTI = (MODE==2) ? 3 : 12;
  constexpr int GRP = 8*NTI;               // 24 / 96
  constexpr int PERSEG = (MODE==2) ? 13*GRP : 4*GRP;   // 312 / 384
  constexpr int M   = (MODE==2) ? 12544 : 3136;
  constexpr int NF  = (MODE==2) ? 192 : 768;

  int id = blockIdx.x;
  int kseg = id / PERSEG; int rem = id % PERSEG;
  int g = rem / GRP, r2 = rem % GRP;
  int mtile = g*8 + (r2 & 7);
  if (mtile >= MTI) return;
  int ntile = r2 >> 3;
  int m0 = mtile*128, n0 = ntile*64;

  __shared__ unsigned short As[3][4096], Bs[3][2048];   // 36 KB

  int tid = threadIdx.x, wv = tid >> 6, lane = tid & 63;
  int l16 = lane & 15, quad = lane >> 4;
  int wy = wv >> 1, wx = wv & 1;

  // staging lane roles: 16 rows x 4 granule-positions per glds call
  int rl = lane >> 2;                       // row within call (0..15)
  int go = ((lane & 3) ^ ((lane >> 3) & 3))*8;   // source granule offset (shorts)

  // A: wave wv stages calls {wv, wv+4} = rows [16wv,16wv+16) and [16(wv+4),..)
  int iyb[2], ixb[2], abase[2];
  #pragma unroll
  for (int j = 0; j < 2; j++){
    int r = (wv + j*4)*16 + rl;
    int m = m0 + r; if (MODE == 3 && m > M-1) m = M-1;   // tail clamp (reads only)
    int ox = m % OW; int t = m / OW; int oy = t % OH; int bb = t / OH;
    iyb[j] = S*oy - P; ixb[j] = S*ox - P;
    abase[j] = ((bb*IH + iyb[j])*IW + ixb[j])*Cin + go;
  }
  // B: wave wv stages call wv = rows [16wv, 16wv+16) of the 64-row B tile
  const unsigned short* pB = Bt + (size_t)(n0 + wv*16 + rl)*K + kseg*K2 + go;

  // k-state for this K-segment (32 | Cin, so a body never crosses a tap)
  int k0 = kseg*K2;
  int c0 = k0 % Cin;
  int gk = k0 / Cin;
  int ky = gk / KW, kx = gk % KW;
  int k0n = 0;

  // fragment read: granule q=quad of row r at position q ^ ((r>>1)&3)
  int xo = (quad ^ ((l16 >> 1) & 3))*8;

  floatx4 acc[4][2];
  #pragma unroll
  for (int mt = 0; mt < 4; mt++)
    #pragma unroll
    for (int nt = 0; nt < 2; nt++) acc[mt][nt] = (floatx4){0.f,0.f,0.f,0.f};

  auto stage = [&](int buf){
    int koff = (ky*IW + kx)*Cin + c0;
    #pragma unroll
    for (int j = 0; j < 2; j++){
      int iy = iyb[j] + ky, ix = ixb[j] + kx;
      const unsigned short* pa = ((unsigned)iy < (unsigned)IH && (unsigned)ix < (unsigned)IW)
                                 ? (Ain + abase[j] + koff) : zp;
      async16(pa, (void*)&As[buf][(wv + j*4)*512]);
    }
    async16(pB + k0n, (void*)&Bs[buf][wv*512]);
    k0n += 32;
    c0 += 32;
    if (c0 == Cin){ c0 = 0; kx++; if (kx == KW){ kx = 0; ky++; } }
  };

  auto compute = [&](int buf){
    short8 b0 = *(const short8*)&Bs[buf][(wx*32      + l16)*32 + xo];
    short8 b1 = *(const short8*)&Bs[buf][(wx*32 + 16 + l16)*32 + xo];
    short8 a0 = *(const short8*)&As[buf][(wy*64       + l16)*32 + xo];
    short8 a1 = *(const short8*)&As[buf][(wy*64 + 16  + l16)*32 + xo];
    short8 a2 = *(const short8*)&As[buf][(wy*64 + 32  + l16)*32 + xo];
    short8 a3 = *(const short8*)&As[buf][(wy*64 + 48  + l16)*32 + xo];
    acc[0][0] = __builtin_amdgcn_mfma_f32_16x16x32_bf16(a0, b0, acc[0][0], 0, 0, 0);
    acc[0][1] = __builtin_amdgcn_mfma_f32_16x16x32_bf16(a0, b1, acc[0][1], 0, 0, 0);
    acc[1][0] = __builtin_amdgcn_mfma_f32_16x16x32_bf16(a1, b0, acc[1][0], 0, 0, 0);
    acc[1][1] = __builtin_amdgcn_mfma_f32_16x16x32_bf16(a1, b1, acc[1][1], 0, 0, 0);
    acc[2][0] = __builtin_amdgcn_mfma_f32_16x16x32_bf16(a2, b0, acc[2][0], 0, 0, 0);
    acc[2][1] = __builtin_amdgcn_mfma_f32_16x16x32_bf16(a2, b1, acc[2][1], 0, 0, 0);
    acc[3][0] = __builtin_amdgcn_mfma_f32_16x16x32_bf16(a3, b0, acc[3][0], 0, 0, 0);
    acc[3][1] = __builtin_amdgcn_mfma_f32_16x16x32_bf16(a3, b1, acc[3][1], 0, 0, 0);
  };

  // depth-2 pipeline over 3 buffers; 6 glds in flight at each barrier.
  stage(0); stage(1);
  int bc = 0;
  for (int i = 0; i < NB - 2; i++){
    PBAR(3);
    int bn = bc + 2; if (bn >= 3) bn -= 3;
    stage(bn);
    compute(bc);
    bc = (bc == 2) ? 0 : bc + 1;
  }
  PBAR(3);
  compute(bc);
  bc = (bc == 2) ? 0 : bc + 1;
  PBAR(0);
  compute(bc);

  // epilogue: f32 atomic accumulate into pre-zeroed partials
  #pragma unroll
  for (int mt = 0; mt < 4; mt++){
    #pragma unroll
    for (int rg = 0; rg < 4; rg++){
      int row = wy*64 + mt*16 + quad*4 + rg;
      int mm = m0 + row;
      if (MODE == 3 && mm >= M) continue;
      #pragma unroll
      for (int nt = 0; nt < 2; nt++){
        int nn = n0 + wx*32 + nt*16 + l16;
        atomicAdd(&pout[(size_t)mm*NF + nn], acc[mt][nt][rg]);
      }
    }
  }
}

// ---------------- combine kernels ----------------
__global__ void comb2(const float* __restrict__ pc, const float* __restrict__ bias,
                      unsigned short* __restrict__ feat){
  int i = blockIdx.x*256 + threadIdx.x;           // 12544*192 = 2408448 exact
  int n = i % 192, m = i / 192;
  feat[(size_t)m*960 + 768 + n] = f2bf(pc[i] + bias[n]);
}
__global__ void comb3(const float* __restrict__ pc, const float* __restrict__ bias,
                      const float* __restrict__ pos, float* __restrict__ out){
  int i = blockIdx.x*256 + threadIdx.x;           // 3136*768 = 2408448 exact
  int n = i % 768, m = i / 768;
  int b2 = m / 49, tt = m - b2*49;
  float v = pc[(size_t)m*768 + n] + bias[n] + pos[(size_t)(1 + tt)*768 + n];
  out[((size_t)(m + b2 + 1))*768 + n] = v;
}

// ---------------- cls row ----------------
__global__ void cls_kernel(const float* __restrict__ cls, const float* __restrict__ pos,
                           float* __restrict__ out){
  int i = blockIdx.x*256 + threadIdx.x;
  if (i >= 64*768) return;
  int e = i % 768, b = i / 768;
  out[(size_t)(b*50)*768 + e] = cls[e] + pos[e];
}

extern "C" void kernel_launch(void* const* d_in, const int* in_sizes, int n_in,
                              void* d_out, int out_size, void* d_ws, size_t ws_size,
                              hipStream_t stream){
  (void)in_sizes; (void)n_in; (void)out_size;
  const float* x    = (const float*)d_in[0];
  const float* w_s1 = (const float*)d_in[1];
  const float* b_s1 = (const float*)d_in[2];
  const float* w_s2 = (const float*)d_in[3];
  const float* b_s2 = (const float*)d_in[4];
  const float* w_p  = (const float*)d_in[5];
  const float* b_p  = (const float*)d_in[6];
  const float* cls  = (const float*)d_in[7];
  const float* pos  = (const float*)d_in[8];
  float* out = (float*)d_out;

  char* ws = (char*)d_ws;
  if (ws_size < 118235136u) return;
  unsigned short* w1p  = (unsigned short*)(ws + 0);
  unsigned short* sp1  = (unsigned short*)(ws + 131072);      // 77.07 MB, dead after conv2
  unsigned short* zp   = (unsigned short*)(ws + 77201408u);
  unsigned short* w2p  = (unsigned short*)(ws + 77266944u);   // 3.6 MB
  unsigned short* w3p  = (unsigned short*)(ws + 80879616u);   // 13.3 MB, written AFTER comb2
  unsigned short* feat = (unsigned short*)(ws + 94150656u);   // 24.1 MB
  unsigned short* xh2  = (unsigned short*)(ws + 77266944u);   // aliases w2p+ (dead by then)
  float* pc2 = (float*)(ws + 80879616u);   // 9.63 MB in w3p's slot (w3p written later)
  float* pc3 = (float*)(ws + 131072);      // 9.83 MB in sp1's region (sp1 dead after conv2)

  prep_w1<<<(192*192 + 255)/256, 256, 0, stream>>>(w_s1, w1p);
  pad_x2<<<(64*3*230*56*8)/256, 256, 0, stream>>>(x, xh2);
  conv1_gemm<<<dim3(1568, 3), 256, 0, stream>>>(xh2, w1p, b_s1, sp1);
  prep_w2<<<(192*9408 + 255)/256, 256, 0, stream>>>(w_s2, w2p);
  prep_zp<<<1, 64, 0, stream>>>((unsigned int*)zp);
  wavelet_kernel<<<64*3*14*14, 256, 0, stream>>>(x, feat);

  zero_f32<<<9408, 256, 0, stream>>>(pc2, 12544*192);
  conv_ks<2><<<624, 256, 0, stream>>>(sp1, w2p, zp, pc2);
  comb2<<<9408, 256, 0, stream>>>(pc2, b_s2, feat);

  prep_w3<<<(768*8640 + 255)/256, 256, 0, stream>>>(w_p, w3p);   // overwrites pc2 (dead)
  zero_f32<<<9600, 256, 0, stream>>>(pc3, 3200*768);
  conv_ks<3><<<768, 256, 0, stream>>>(feat, w3p, zp, pc3);
  comb3<<<9408, 256, 0, stream>>>(pc3, b_p, pos, out);
  cls_kernel<<<(64*768 + 255)/256, 256, 0, stream>>>(cls, pos, out);
}